// Round 3
// baseline (477.309 us; speedup 1.0000x reference)
//
#include <hip/hip_runtime.h>

#define NB 8192
#define COMPS 4096
#define DIM 768

typedef _Float16 half8_t __attribute__((ext_vector_type(8)));
typedef float floatx4 __attribute__((ext_vector_type(4)));
typedef unsigned short ushort4_t __attribute__((ext_vector_type(4)));
typedef unsigned short ushort8_t __attribute__((ext_vector_type(8)));

typedef __attribute__((address_space(1))) const void* gas_ptr;
typedef __attribute__((address_space(3))) void* las_ptr;

__device__ __forceinline__ void gl_lds16(const _Float16* g, _Float16* l) {
  __builtin_amdgcn_global_load_lds((gas_ptr)(const void*)g, (las_ptr)(void*)l, 16, 0, 0);
}

__device__ __forceinline__ unsigned long long pack_min(float v, int col) {
  unsigned u = __float_as_uint(v);
  u = (u & 0x80000000u) ? ~u : (u | 0x80000000u);
  return ((unsigned long long)u << 32) | (unsigned)col;
}

// ---------------- prep: fp32 -> fp16 hi/lo split ----------------
__global__ void k_prep_e(const float* __restrict__ e,
                         _Float16* __restrict__ ehi, _Float16* __restrict__ elo) {
  int id = blockIdx.x * 256 + threadIdx.x;     // float4 index
  float4 v = ((const float4*)e)[id];
  ushort4_t h, l;
  float xs[4] = {v.x, v.y, v.z, v.w};
#pragma unroll
  for (int q = 0; q < 4; ++q) {
    _Float16 hh = (_Float16)xs[q];
    _Float16 ll = (_Float16)(xs[q] - (float)hh);
    h[q] = __builtin_bit_cast(unsigned short, hh);
    l[q] = __builtin_bit_cast(unsigned short, ll);
  }
  ((ushort4_t*)ehi)[id] = h;
  ((ushort4_t*)elo)[id] = l;
}

// contents: hi/lo split + fp32 row norms. 192 threads, 1 block per row.
__global__ void k_prep_c(const float* __restrict__ c,
                         _Float16* __restrict__ chi, _Float16* __restrict__ clo,
                         float* __restrict__ cnorm) {
  int i = blockIdx.x, t = threadIdx.x;         // 192 threads, 768 = 192*4
  float4 v = ((const float4*)c)[i * 192 + t];
  float xs[4] = {v.x, v.y, v.z, v.w};
  ushort4_t h, l;
  float s = 0.f;
#pragma unroll
  for (int q = 0; q < 4; ++q) {
    _Float16 hh = (_Float16)xs[q];
    _Float16 ll = (_Float16)(xs[q] - (float)hh);
    h[q] = __builtin_bit_cast(unsigned short, hh);
    l[q] = __builtin_bit_cast(unsigned short, ll);
    s = fmaf(xs[q], xs[q], s);
  }
  ((ushort4_t*)chi)[i * 192 + t] = h;
  ((ushort4_t*)clo)[i * 192 + t] = l;
#pragma unroll
  for (int o = 32; o; o >>= 1) s += __shfl_down(s, o);
  __shared__ float red[3];
  if ((t & 63) == 0) red[t >> 6] = s;
  __syncthreads();
  if (t == 0) cnorm[i] = red[0] + red[1] + red[2];
}

// ---------------- GEMM1: dist + fused argmin ----------------
// dist'[i][j] = ||c_j||^2 - 2 * e_i . c_j  via fp16 hi/lo split (hh+hl+lh)
// Staging: global_load_lds w=16, linear LDS dest, pre-swizzled global source.
__launch_bounds__(256)
__global__ void k_gemm1(const _Float16* __restrict__ ehi, const _Float16* __restrict__ elo,
                        const _Float16* __restrict__ chi, const _Float16* __restrict__ clo,
                        const float* __restrict__ cnorm,
                        unsigned long long* __restrict__ packed) {
  __shared__ _Float16 Ah[128 * 32], Al[128 * 32], Bh[128 * 32], Bl[128 * 32];
  int tid = threadIdx.x;
  int lane = tid & 63, w = tid >> 6;
  int wr = w >> 1, wc = w & 1;
  int g = lane >> 4, rl = lane & 15;
  int i0 = blockIdx.x * 128, j0 = blockIdx.y * 128;

  // staging assignment: wave w stages buffer w (8 x 1KB wave-instructions)
  int l4 = lane >> 2, cp = lane & 3;
  int cch = (cp - l4 - (l4 >> 2)) & 3;         // inverse swizzle (q*16 rows ≡ 0 mod 4)
  const _Float16* gsrc;
  _Float16* dbuf;
  if (w == 0)      { gsrc = ehi + (size_t)i0 * DIM; dbuf = Ah; }
  else if (w == 1) { gsrc = elo + (size_t)i0 * DIM; dbuf = Al; }
  else if (w == 2) { gsrc = chi + (size_t)j0 * DIM; dbuf = Bh; }
  else             { gsrc = clo + (size_t)j0 * DIM; dbuf = Bl; }
  gsrc += (size_t)l4 * DIM + cch * 8;          // per-lane source offset
  _Float16* dst = dbuf + lane * 8;             // linear LDS dest (lane*16B)

  floatx4 acc[4][4] = {};

  for (int kt = 0; kt < DIM; kt += 32) {
    __syncthreads();
#pragma unroll
    for (int q = 0; q < 8; ++q)
      gl_lds16(gsrc + kt + (size_t)(q * 16) * DIM, dst + q * 512);
    __syncthreads();

    half8_t ah[4], al[4];
#pragma unroll
    for (int m = 0; m < 4; ++m) {
      int r = wr * 64 + m * 16 + rl;
      int slot = (g + r + (r >> 2)) & 3;
      ah[m] = *(half8_t*)&Ah[r * 32 + slot * 8];
      al[m] = *(half8_t*)&Al[r * 32 + slot * 8];
    }
#pragma unroll
    for (int n = 0; n < 4; ++n) {
      int r = wc * 64 + n * 16 + rl;
      int slot = (g + r + (r >> 2)) & 3;
      half8_t bh = *(half8_t*)&Bh[r * 32 + slot * 8];
      half8_t bl = *(half8_t*)&Bl[r * 32 + slot * 8];
#pragma unroll
      for (int m = 0; m < 4; ++m) {
        acc[m][n] = __builtin_amdgcn_mfma_f32_16x16x32_f16(ah[m], bh, acc[m][n], 0, 0, 0);
        acc[m][n] = __builtin_amdgcn_mfma_f32_16x16x32_f16(ah[m], bl, acc[m][n], 0, 0, 0);
        acc[m][n] = __builtin_amdgcn_mfma_f32_16x16x32_f16(al[m], bh, acc[m][n], 0, 0, 0);
      }
    }
  }

  // epilogue: per-row argmin over this block's 128 cols, merge via atomicMin
  float cn[4];
#pragma unroll
  for (int n = 0; n < 4; ++n) cn[n] = cnorm[j0 + wc * 64 + n * 16 + rl];

#pragma unroll
  for (int m = 0; m < 4; ++m) {
#pragma unroll
    for (int j = 0; j < 4; ++j) {
      int row = i0 + wr * 64 + m * 16 + g * 4 + j;
      float best = 3.0e38f;
      int bcol = 0;
#pragma unroll
      for (int n = 0; n < 4; ++n) {
        float d = fmaf(-2.0f, acc[m][n][j], cn[n]);
        int col = j0 + wc * 64 + n * 16 + rl;
        if (d < best) { best = d; bcol = col; }
      }
      unsigned long long pk = pack_min(best, bcol);
#pragma unroll
      for (int o = 1; o < 16; o <<= 1) {
        unsigned long long other = __shfl_xor(pk, o);
        if (other < pk) pk = other;
      }
      if (rl == 0) atomicMin(&packed[row], pk);
    }
  }
}

// ---------------- scatter: freq + per-comp sums ----------------
__global__ void k_scatter(const float* __restrict__ e,
                          const unsigned long long* __restrict__ packed,
                          float* __restrict__ freq, float* __restrict__ sums) {
  int i = blockIdx.x, t = threadIdx.x;
  int idx = (int)(packed[i] & 0xffffffffULL);
  if (t == 0) unsafeAtomicAdd(&freq[idx], 1.0f);
#pragma unroll
  for (int r = 0; r < 3; ++r) {
    int d = t + 256 * r;
    unsafeAtomicAdd(&sums[(size_t)idx * DIM + d], e[(size_t)i * DIM + d]);
  }
}

// ---------------- avg (transposed, fp16): avgT[d][j] ----------------
__global__ void k_avgt(const float* __restrict__ sums, const float* __restrict__ freq,
                       const float* __restrict__ cont, _Float16* __restrict__ avgT) {
  __shared__ float tile[64][65];
  int jb = blockIdx.x, db = blockIdx.y, t = threadIdx.x;
#pragma unroll
  for (int v = 0; v < 4; ++v) {
    int id = t + 256 * v;
    int r = id >> 4, c4 = id & 15;
    int j = jb * 64 + r;
    float f = freq[j];
    size_t o = (size_t)j * 192 + db * 16 + c4;
    float4 a;
    if (f > 0.f) {
      float4 s = ((const float4*)sums)[o];
      a.x = s.x / f; a.y = s.y / f; a.z = s.z / f; a.w = s.w / f;
    } else {
      a = ((const float4*)cont)[o];
    }
    tile[r][c4 * 4 + 0] = a.x; tile[r][c4 * 4 + 1] = a.y;
    tile[r][c4 * 4 + 2] = a.z; tile[r][c4 * 4 + 3] = a.w;
  }
  __syncthreads();
#pragma unroll
  for (int v = 0; v < 2; ++v) {
    int id = t + 256 * v;
    int drow = id >> 3, c8 = id & 7;
    int d = db * 64 + drow;
    ushort8_t h;
#pragma unroll
    for (int k = 0; k < 8; ++k) {
      _Float16 hv = (_Float16)tile[c8 * 8 + k][drow];
      h[k] = __builtin_bit_cast(unsigned short, hv);
    }
    *(ushort8_t*)&avgT[(size_t)d * COMPS + jb * 64 + c8 * 8] = h;
  }
}

// ---------------- weights fp16 + row sums ----------------
__global__ void k_expw(const float* __restrict__ gd, const float* __restrict__ sigma,
                       _Float16* __restrict__ W, float* __restrict__ wsum) {
  int i = blockIdx.x, t = threadIdx.x;
  float sg = sigma[0];
  float inv = -1.0f / (2.0f * sg * sg);
  float s = 0.f;
#pragma unroll
  for (int v = 0; v < 4; ++v) {
    int id = t + 256 * v;
    float4 gv = ((const float4*)gd)[(size_t)i * 1024 + id];
    float w0 = expf(gv.x * inv), w1 = expf(gv.y * inv);
    float w2 = expf(gv.z * inv), w3 = expf(gv.w * inv);
    s += (w0 + w1) + (w2 + w3);
    ushort4_t h;
    h[0] = __builtin_bit_cast(unsigned short, (_Float16)w0);
    h[1] = __builtin_bit_cast(unsigned short, (_Float16)w1);
    h[2] = __builtin_bit_cast(unsigned short, (_Float16)w2);
    h[3] = __builtin_bit_cast(unsigned short, (_Float16)w3);
    ((ushort4_t*)W)[(size_t)i * 1024 + id] = h;
  }
#pragma unroll
  for (int o = 32; o; o >>= 1) s += __shfl_down(s, o);
  __shared__ float red[4];
  if ((t & 63) == 0) red[t >> 6] = s;
  __syncthreads();
  if (t == 0) wsum[i] = (red[0] + red[1]) + (red[2] + red[3]);
}

// ---------------- GEMM2 (split-K x4): num += W @ avg ----------------
__launch_bounds__(256)
__global__ void k_gemm2(const _Float16* __restrict__ W, const _Float16* __restrict__ avgT,
                        float* __restrict__ num) {
  __shared__ _Float16 At[128 * 32], Bt[128 * 32];
  int tid = threadIdx.x;
  int lane = tid & 63, w = tid >> 6;
  int wr = w >> 1, wc = w & 1;
  int g = lane >> 4, rl = lane & 15;
  int i0 = blockIdx.x * 128, d0 = blockIdx.y * 128;
  int kc = blockIdx.z;

  // staging: waves {0,1} -> At, waves {2,3} -> Bt; 4 wave-insts each
  int l4 = lane >> 2, cp = lane & 3;
  int cch = (cp - l4 - (l4 >> 2)) & 3;
  const _Float16* gsrc = (w < 2) ? (W + (size_t)i0 * COMPS) : (avgT + (size_t)d0 * COMPS);
  _Float16* dbuf = (w < 2) ? At : Bt;
  int qbase = (w & 1) * 4;
  gsrc += (size_t)(qbase * 16 + l4) * COMPS + cch * 8;
  _Float16* dst = dbuf + qbase * 512 + lane * 8;

  floatx4 acc[4][4] = {};

  int kend = kc * 1024 + 1024;
  for (int kt = kc * 1024; kt < kend; kt += 32) {
    __syncthreads();
#pragma unroll
    for (int q = 0; q < 4; ++q)
      gl_lds16(gsrc + kt + (size_t)(q * 16) * COMPS, dst + q * 512);
    __syncthreads();

    half8_t a[4];
#pragma unroll
    for (int m = 0; m < 4; ++m) {
      int r = wr * 64 + m * 16 + rl;
      int slot = (g + r + (r >> 2)) & 3;
      a[m] = *(half8_t*)&At[r * 32 + slot * 8];
    }
#pragma unroll
    for (int n = 0; n < 4; ++n) {
      int r = wc * 64 + n * 16 + rl;
      int slot = (g + r + (r >> 2)) & 3;
      half8_t b = *(half8_t*)&Bt[r * 32 + slot * 8];
#pragma unroll
      for (int m = 0; m < 4; ++m)
        acc[m][n] = __builtin_amdgcn_mfma_f32_16x16x32_f16(a[m], b, acc[m][n], 0, 0, 0);
    }
  }

#pragma unroll
  for (int m = 0; m < 4; ++m) {
#pragma unroll
    for (int j = 0; j < 4; ++j) {
      int i = i0 + wr * 64 + m * 16 + g * 4 + j;
#pragma unroll
      for (int n = 0; n < 4; ++n) {
        int d = d0 + wc * 64 + n * 16 + rl;
        unsafeAtomicAdd(&num[(size_t)i * DIM + d], acc[m][n][j]);
      }
    }
  }
}

// ---------------- epilogue: update/where + rowsq + delta ----------------
__global__ void k_update(const float* __restrict__ num, const float* __restrict__ freq,
                         const float* __restrict__ wsum, const float* __restrict__ cont,
                         float* __restrict__ out) {
  int i = blockIdx.x, t = threadIdx.x;   // 192 threads, 768 = 192*4
  float f = freq[i];
  bool used = f > 0.f;
  float inv = used ? 1.0f / wsum[i] : 0.f;
  float4 nv = ((const float4*)num)[i * 192 + t];
  float4 cv = ((const float4*)cont)[i * 192 + t];
  float nn[4] = {nv.x, nv.y, nv.z, nv.w};
  float cc[4] = {cv.x, cv.y, cv.z, cv.w};
  float s = 0.f, o[4];
#pragma unroll
  for (int q = 0; q < 4; ++q) {
    float v = used ? nn[q] * inv : cc[q];
    o[q] = v;
    float df = v - cc[q];
    s = fmaf(df, df, s);
  }
  size_t base = 1 + (size_t)i * DIM + t * 4;
  out[base] = o[0]; out[base + 1] = o[1]; out[base + 2] = o[2]; out[base + 3] = o[3];
#pragma unroll
  for (int off = 32; off; off >>= 1) s += __shfl_down(s, off);
  __shared__ float red[3];
  if ((t & 63) == 0) red[t >> 6] = s;
  __syncthreads();
  if (t == 0) unsafeAtomicAdd(out, sqrtf(red[0] + red[1] + red[2]));
}

extern "C" void kernel_launch(void* const* d_in, const int* in_sizes, int n_in,
                              void* d_out, int out_size, void* d_ws, size_t ws_size,
                              hipStream_t stream) {
  const float* e = (const float*)d_in[0];       // [8192, 768]
  const float* cont = (const float*)d_in[1];    // [64, 64, 768]
  const float* gd = (const float*)d_in[2];      // [4096, 4096]
  const float* sigma = (const float*)d_in[3];   // [1]
  float* out = (float*)d_out;                   // [1 + 4096*768]

  char* ws = (char*)d_ws;
  size_t off = 0;
  auto take = [&](size_t bytes) { char* p = ws + off; off += (bytes + 255) & ~(size_t)255; return p; };

  unsigned long long* packed = (unsigned long long*)take(NB * 8);
  float* freq  = (float*)take(COMPS * 4);
  float* wsum  = (float*)take(COMPS * 4);
  float* cnorm = (float*)take(COMPS * 4);
  float* sums  = (float*)take((size_t)COMPS * DIM * 4);
  float* num   = sums;                           // alias: sums dead after k_avgt
  _Float16* avgT = (_Float16*)take((size_t)DIM * COMPS * 2);
  // union region: {ehi, elo, chi, clo} during GEMM1 phase; W afterwards
  char* U = take((size_t)NB * DIM * 2 * 2 + (size_t)COMPS * DIM * 2 * 2);
  _Float16* ehi = (_Float16*)U;
  _Float16* elo = (_Float16*)(U + (size_t)NB * DIM * 2);
  _Float16* chi = (_Float16*)(U + (size_t)NB * DIM * 4);
  _Float16* clo = (_Float16*)(U + (size_t)NB * DIM * 4 + (size_t)COMPS * DIM * 2);
  _Float16* W = (_Float16*)U;                    // aliases e/c halves (dead by then)

  hipMemsetAsync(packed, 0xFF, NB * 8, stream);
  hipMemsetAsync(freq, 0, COMPS * 4, stream);
  hipMemsetAsync(sums, 0, (size_t)COMPS * DIM * 4, stream);
  hipMemsetAsync(out, 0, 4, stream);

  k_prep_e<<<(NB * DIM / 4) / 256, 256, 0, stream>>>(e, ehi, elo);
  k_prep_c<<<COMPS, 192, 0, stream>>>(cont, chi, clo, cnorm);
  k_gemm1<<<dim3(NB / 128, COMPS / 128), 256, 0, stream>>>(ehi, elo, chi, clo, cnorm, packed);
  k_scatter<<<NB, 256, 0, stream>>>(e, packed, freq, sums);
  k_avgt<<<dim3(COMPS / 64, DIM / 64), 256, 0, stream>>>(sums, freq, cont, avgT);
  hipMemsetAsync(num, 0, (size_t)COMPS * DIM * 4, stream);   // re-zero aliased buffer
  k_expw<<<COMPS, 256, 0, stream>>>(gd, sigma, W, wsum);
  k_gemm2<<<dim3(COMPS / 128, DIM / 128, 4), 256, 0, stream>>>(W, avgT, num);
  k_update<<<COMPS, 192, 0, stream>>>(num, freq, wsum, cont, out);
}

// Round 4
// 397.382 us; speedup vs baseline: 1.2011x; 1.2011x over previous
//
#include <hip/hip_runtime.h>

#define NB 8192
#define COMPS 4096
#define DIM 768

typedef _Float16 half8_t __attribute__((ext_vector_type(8)));
typedef float floatx4 __attribute__((ext_vector_type(4)));
typedef unsigned short ushort4_t __attribute__((ext_vector_type(4)));
typedef unsigned short ushort8_t __attribute__((ext_vector_type(8)));

typedef __attribute__((address_space(1))) const void* gas_ptr;
typedef __attribute__((address_space(3))) void* las_ptr;

__device__ __forceinline__ void gl_lds16(const _Float16* g, _Float16* l) {
  __builtin_amdgcn_global_load_lds((gas_ptr)(const void*)g, (las_ptr)(void*)l, 16, 0, 0);
}

__device__ __forceinline__ unsigned long long pack_min(float v, int col) {
  unsigned u = __float_as_uint(v);
  u = (u & 0x80000000u) ? ~u : (u | 0x80000000u);
  return ((unsigned long long)u << 32) | (unsigned)col;
}

// ---------------- prep: fp32 -> fp16 hi/lo split ----------------
__global__ void k_prep_e(const float* __restrict__ e,
                         _Float16* __restrict__ ehi, _Float16* __restrict__ elo) {
  int id = blockIdx.x * 256 + threadIdx.x;     // float4 index
  float4 v = ((const float4*)e)[id];
  ushort4_t h, l;
  float xs[4] = {v.x, v.y, v.z, v.w};
#pragma unroll
  for (int q = 0; q < 4; ++q) {
    _Float16 hh = (_Float16)xs[q];
    _Float16 ll = (_Float16)(xs[q] - (float)hh);
    h[q] = __builtin_bit_cast(unsigned short, hh);
    l[q] = __builtin_bit_cast(unsigned short, ll);
  }
  ((ushort4_t*)ehi)[id] = h;
  ((ushort4_t*)elo)[id] = l;
}

// contents: hi/lo split + fp32 row norms. 192 threads, 1 block per row.
__global__ void k_prep_c(const float* __restrict__ c,
                         _Float16* __restrict__ chi, _Float16* __restrict__ clo,
                         float* __restrict__ cnorm) {
  int i = blockIdx.x, t = threadIdx.x;         // 192 threads, 768 = 192*4
  float4 v = ((const float4*)c)[i * 192 + t];
  float xs[4] = {v.x, v.y, v.z, v.w};
  ushort4_t h, l;
  float s = 0.f;
#pragma unroll
  for (int q = 0; q < 4; ++q) {
    _Float16 hh = (_Float16)xs[q];
    _Float16 ll = (_Float16)(xs[q] - (float)hh);
    h[q] = __builtin_bit_cast(unsigned short, hh);
    l[q] = __builtin_bit_cast(unsigned short, ll);
    s = fmaf(xs[q], xs[q], s);
  }
  ((ushort4_t*)chi)[i * 192 + t] = h;
  ((ushort4_t*)clo)[i * 192 + t] = l;
#pragma unroll
  for (int o = 32; o; o >>= 1) s += __shfl_down(s, o);
  __shared__ float red[3];
  if ((t & 63) == 0) red[t >> 6] = s;
  __syncthreads();
  if (t == 0) cnorm[i] = red[0] + red[1] + red[2];
}

// ---------------- E matrix: E[p][q] = exp(-(p-q)^2/(2 sigma^2)), row sums ----
__global__ void k_exps(const float* __restrict__ sigma,
                       float* __restrict__ E, float* __restrict__ rE) {
  int i = blockIdx.x, j = threadIdx.x;         // 64 x 64
  float sg = sigma[0];
  float inv = -1.0f / (2.0f * sg * sg);
  float d = (float)(i - j);
  float v = expf(d * d * inv);
  E[i * 64 + j] = v;
  float s = v;
#pragma unroll
  for (int o = 32; o; o >>= 1) s += __shfl_down(s, o);
  if (j == 0) rE[i] = s;
}

// ---------------- GEMM1: dist + fused argmin (BK=64, XOR swizzle) ----------
__launch_bounds__(256)
__global__ void k_gemm1(const _Float16* __restrict__ ehi, const _Float16* __restrict__ elo,
                        const _Float16* __restrict__ chi, const _Float16* __restrict__ clo,
                        const float* __restrict__ cnorm,
                        unsigned long long* __restrict__ packed) {
  __shared__ _Float16 Ah[128 * 64], Al[128 * 64], Bh[128 * 64], Bl[128 * 64]; // 64 KB
  int tid = threadIdx.x;
  int lane = tid & 63, w = tid >> 6;
  int wr = w >> 1, wc = w & 1;
  int g = lane >> 4, rl = lane & 15;
  int i0 = blockIdx.x * 128, j0 = blockIdx.y * 128;

  // staging: wave w stages its whole 16KB buffer with 16 gl_lds16.
  // LDS rows are 128B (=32 banks), chunk p = c ^ (r&7). Linear LDS dest,
  // inverse-swizzled global source (rule #21).
  int lr = lane >> 3, lc = lane & 7;
  int cch = lc ^ lr;                           // logical chunk for this lane
  const _Float16* gsrc;
  _Float16* dbuf;
  if (w == 0)      { gsrc = ehi + (size_t)i0 * DIM; dbuf = Ah; }
  else if (w == 1) { gsrc = elo + (size_t)i0 * DIM; dbuf = Al; }
  else if (w == 2) { gsrc = chi + (size_t)j0 * DIM; dbuf = Bh; }
  else             { gsrc = clo + (size_t)j0 * DIM; dbuf = Bl; }
  gsrc += (size_t)lr * DIM + cch * 8;
  _Float16* dst = dbuf + lane * 8;             // linear LDS dest (lane*16B)

  floatx4 acc[4][4] = {};

  for (int kt = 0; kt < DIM; kt += 64) {
    __syncthreads();
#pragma unroll
    for (int q = 0; q < 16; ++q)
      gl_lds16(gsrc + kt + (size_t)(q * 8) * DIM, dst + q * 512);
    __syncthreads();

#pragma unroll
    for (int s = 0; s < 2; ++s) {
      half8_t ah[4], al[4];
#pragma unroll
      for (int m = 0; m < 4; ++m) {
        int r = wr * 64 + m * 16 + rl;
        int p = (s * 4 + g) ^ (rl & 7);
        ah[m] = *(half8_t*)&Ah[r * 64 + p * 8];
        al[m] = *(half8_t*)&Al[r * 64 + p * 8];
      }
#pragma unroll
      for (int n = 0; n < 4; ++n) {
        int r = wc * 64 + n * 16 + rl;
        int p = (s * 4 + g) ^ (rl & 7);
        half8_t bh = *(half8_t*)&Bh[r * 64 + p * 8];
        half8_t bl = *(half8_t*)&Bl[r * 64 + p * 8];
#pragma unroll
        for (int m = 0; m < 4; ++m) {
          acc[m][n] = __builtin_amdgcn_mfma_f32_16x16x32_f16(ah[m], bh, acc[m][n], 0, 0, 0);
          acc[m][n] = __builtin_amdgcn_mfma_f32_16x16x32_f16(ah[m], bl, acc[m][n], 0, 0, 0);
          acc[m][n] = __builtin_amdgcn_mfma_f32_16x16x32_f16(al[m], bh, acc[m][n], 0, 0, 0);
        }
      }
    }
  }

  // epilogue: per-row argmin over this block's 128 cols, merge via atomicMin
  float cn[4];
#pragma unroll
  for (int n = 0; n < 4; ++n) cn[n] = cnorm[j0 + wc * 64 + n * 16 + rl];

#pragma unroll
  for (int m = 0; m < 4; ++m) {
#pragma unroll
    for (int j = 0; j < 4; ++j) {
      int row = i0 + wr * 64 + m * 16 + g * 4 + j;
      float best = 3.0e38f;
      int bcol = 0;
#pragma unroll
      for (int n = 0; n < 4; ++n) {
        float d = fmaf(-2.0f, acc[m][n][j], cn[n]);
        int col = j0 + wc * 64 + n * 16 + rl;
        if (d < best) { best = d; bcol = col; }
      }
      unsigned long long pk = pack_min(best, bcol);
#pragma unroll
      for (int o = 1; o < 16; o <<= 1) {
        unsigned long long other = __shfl_xor(pk, o);
        if (other < pk) pk = other;
      }
      if (rl == 0) atomicMin(&packed[row], pk);
    }
  }
}

// ---------------- scatter: freq + per-comp sums ----------------
__global__ void k_scatter(const float* __restrict__ e,
                          const unsigned long long* __restrict__ packed,
                          float* __restrict__ freq, float* __restrict__ sums) {
  int i = blockIdx.x, t = threadIdx.x;
  int idx = (int)(packed[i] & 0xffffffffULL);
  if (t == 0) unsafeAtomicAdd(&freq[idx], 1.0f);
#pragma unroll
  for (int r = 0; r < 3; ++r) {
    int d = t + 256 * r;
    unsafeAtomicAdd(&sums[(size_t)idx * DIM + d], e[(size_t)i * DIM + d]);
  }
}

// ---------------- T1[a][b][d] = sum_b' E[b,b'] * avg[(a,b')][d] ------------
// grid (64 a, 6 dblk), block 256. avg computed on the fly from sums/freq/cont.
__global__ void k_t1(const float* __restrict__ sums, const float* __restrict__ freq,
                     const float* __restrict__ cont, const float* __restrict__ E,
                     float* __restrict__ T1) {
  __shared__ float S[64 * 128];   // 32 KB: avg slab [b'][d]
  __shared__ float Esh[64 * 64];  // 16 KB
  int a = blockIdx.x, db = blockIdx.y, t = threadIdx.x;
#pragma unroll
  for (int it = 0; it < 8; ++it) {
    int id = t + 256 * it;                     // float4 id 0..2047
    int row = id >> 5, c4 = id & 31;
    int comp = a * 64 + row;
    float f = freq[comp];
    size_t o = (size_t)comp * 192 + db * 32 + c4;
    floatx4 v;
    if (f > 0.f) {
      floatx4 sv = ((const floatx4*)sums)[o];
      float inv = 1.0f / f;
      v = sv * inv;
    } else v = ((const floatx4*)cont)[o];
    ((floatx4*)S)[id] = v;
  }
#pragma unroll
  for (int it = 0; it < 4; ++it) {
    int id = t + 256 * it;
    ((floatx4*)Esh)[id] = ((const floatx4*)E)[id];
  }
  __syncthreads();

  int d4 = t & 31, b0 = (t >> 5) * 8;
  floatx4 acc[8] = {};
  for (int bp = 0; bp < 64; ++bp) {
    floatx4 sv = ((floatx4*)S)[bp * 32 + d4];
#pragma unroll
    for (int b = 0; b < 8; ++b)
      acc[b] += Esh[(b0 + b) * 64 + bp] * sv;
  }
#pragma unroll
  for (int b = 0; b < 8; ++b)
    ((floatx4*)T1)[(size_t)(a * 64 + b0 + b) * 192 + db * 32 + d4] = acc[b];
}

// ---------------- num[a][b][d] = sum_a' E[a,a'] T1[a'][b][d]; fused update --
// grid (64 b, 6 dblk), block 256.
__global__ void k_wnum(const float* __restrict__ T1, const float* __restrict__ E,
                       const float* __restrict__ rE, const float* __restrict__ freq,
                       const float* __restrict__ cont, float* __restrict__ out) {
  __shared__ float S[64 * 128];   // T1 slab [a'][d]
  __shared__ float Esh[64 * 64];
  int b = blockIdx.x, db = blockIdx.y, t = threadIdx.x;
#pragma unroll
  for (int it = 0; it < 8; ++it) {
    int id = t + 256 * it;
    int ap = id >> 5, c4 = id & 31;
    ((floatx4*)S)[id] = ((const floatx4*)T1)[(size_t)(ap * 64 + b) * 192 + db * 32 + c4];
  }
#pragma unroll
  for (int it = 0; it < 4; ++it) {
    int id = t + 256 * it;
    ((floatx4*)Esh)[id] = ((const floatx4*)E)[id];
  }
  __syncthreads();

  int d4 = t & 31, a0 = (t >> 5) * 8;
  floatx4 acc[8] = {};
  for (int ap = 0; ap < 64; ++ap) {
    floatx4 tv = ((floatx4*)S)[ap * 32 + d4];
#pragma unroll
    for (int a = 0; a < 8; ++a)
      acc[a] += Esh[(a0 + a) * 64 + ap] * tv;
  }

  float rb = rE[b];
#pragma unroll
  for (int a = 0; a < 8; ++a) {
    int comp = (a0 + a) * 64 + b;
    float f = freq[comp];
    floatx4 cv = ((const floatx4*)cont)[(size_t)comp * 192 + db * 32 + d4];
    floatx4 val;
    if (f > 0.f) {
      float inv = 1.0f / (rE[a0 + a] * rb);
      val = acc[a] * inv;
    } else val = cv;
    size_t base = 1 + (size_t)comp * DIM + db * 128 + d4 * 4;
    out[base] = val[0]; out[base + 1] = val[1];
    out[base + 2] = val[2]; out[base + 3] = val[3];
  }
}

// ---------------- delta = sum_c || new_c - old_c || ----------------
__global__ void k_delta(const float* __restrict__ cont, float* __restrict__ out) {
  int i = blockIdx.x, t = threadIdx.x;   // 192 threads
  const float* nrow = out + 1 + (size_t)i * DIM;
  floatx4 cv = ((const floatx4*)cont)[i * 192 + t];
  float n0 = nrow[t * 4], n1 = nrow[t * 4 + 1], n2 = nrow[t * 4 + 2], n3 = nrow[t * 4 + 3];
  float d0 = n0 - cv[0], d1 = n1 - cv[1], d2 = n2 - cv[2], d3 = n3 - cv[3];
  float s = d0 * d0 + d1 * d1 + d2 * d2 + d3 * d3;
#pragma unroll
  for (int o = 32; o; o >>= 1) s += __shfl_down(s, o);
  __shared__ float red[3];
  if ((t & 63) == 0) red[t >> 6] = s;
  __syncthreads();
  if (t == 0) unsafeAtomicAdd(out, sqrtf(red[0] + red[1] + red[2]));
}

extern "C" void kernel_launch(void* const* d_in, const int* in_sizes, int n_in,
                              void* d_out, int out_size, void* d_ws, size_t ws_size,
                              hipStream_t stream) {
  const float* e = (const float*)d_in[0];       // [8192, 768]
  const float* cont = (const float*)d_in[1];    // [64, 64, 768]
  // d_in[2] (grid_dists) no longer read: W = E (x) E separable
  const float* sigma = (const float*)d_in[3];   // [1]
  float* out = (float*)d_out;                   // [1 + 4096*768]

  char* ws = (char*)d_ws;
  size_t off = 0;
  auto take = [&](size_t bytes) { char* p = ws + off; off += (bytes + 255) & ~(size_t)255; return p; };

  unsigned long long* packed = (unsigned long long*)take(NB * 8);
  float* freq  = (float*)take(COMPS * 4);
  float* cnorm = (float*)take(COMPS * 4);
  float* E     = (float*)take(64 * 64 * 4);
  float* rE    = (float*)take(64 * 4);
  float* sums  = (float*)take((size_t)COMPS * DIM * 4);
  // union region: {ehi, elo, chi, clo} during GEMM1; T1 aliases chi+clo after
  char* U = take((size_t)NB * DIM * 2 * 2 + (size_t)COMPS * DIM * 2 * 2);
  _Float16* ehi = (_Float16*)U;
  _Float16* elo = (_Float16*)(U + (size_t)NB * DIM * 2);
  _Float16* chi = (_Float16*)(U + (size_t)NB * DIM * 4);
  _Float16* clo = (_Float16*)(U + (size_t)NB * DIM * 4 + (size_t)COMPS * DIM * 2);
  float* T1 = (float*)(U + (size_t)NB * DIM * 4);   // 12.58MB = chi+clo region

  hipMemsetAsync(packed, 0xFF, NB * 8, stream);
  hipMemsetAsync(freq, 0, COMPS * 4, stream);
  hipMemsetAsync(sums, 0, (size_t)COMPS * DIM * 4, stream);
  hipMemsetAsync(out, 0, 4, stream);

  k_prep_e<<<(NB * DIM / 4) / 256, 256, 0, stream>>>(e, ehi, elo);
  k_prep_c<<<COMPS, 192, 0, stream>>>(cont, chi, clo, cnorm);
  k_exps<<<64, 64, 0, stream>>>(sigma, E, rE);
  k_gemm1<<<dim3(NB / 128, COMPS / 128), 256, 0, stream>>>(ehi, elo, chi, clo, cnorm, packed);
  k_scatter<<<NB, 256, 0, stream>>>(e, packed, freq, sums);
  k_t1<<<dim3(64, 6), 256, 0, stream>>>(sums, freq, cont, E, T1);
  k_wnum<<<dim3(64, 6), 256, 0, stream>>>(T1, E, rE, freq, cont, out);
  k_delta<<<COMPS, 192, 0, stream>>>(cont, out);
}